// Round 1
// baseline (673.288 us; speedup 1.0000x reference)
//
#include <hip/hip_runtime.h>

#define NN 50000
#define NE 800000
#define CH 128
#define EPSV 1e-5f

// ---------------- CSR build (dst-sorted pull aggregation) ----------------

__global__ void k_hist(const int* __restrict__ dst, int* __restrict__ deg) {
    int e = blockIdx.x * blockDim.x + threadIdx.x;
    if (e < NE) atomicAdd(&deg[dst[e]], 1);
}

// single-block exclusive scan over NN counts -> row_ptr[NN+1]
__global__ void k_scan(const int* __restrict__ deg, int* __restrict__ row_ptr) {
    __shared__ int wsum[16];
    const int t = threadIdx.x;
    const int lane = t & 63;
    const int wid = t >> 6;
    int carry = 0;
    for (int base = 0; base < NN; base += 1024) {
        int i = base + t;
        int v = (i < NN) ? deg[i] : 0;
        int x = v;
        #pragma unroll
        for (int off = 1; off < 64; off <<= 1) {
            int y = __shfl_up(x, off, 64);
            if (lane >= off) x += y;
        }
        if (lane == 63) wsum[wid] = x;
        __syncthreads();
        if (wid == 0 && lane < 16) {
            int s = wsum[lane];
            #pragma unroll
            for (int off = 1; off < 16; off <<= 1) {
                int y = __shfl_up(s, off, 16);
                if (lane >= off) s += y;
            }
            wsum[lane] = s;
        }
        __syncthreads();
        int wbase = (wid > 0) ? wsum[wid - 1] : 0;
        if (i < NN) row_ptr[i] = carry + wbase + x - v;  // exclusive prefix
        carry += wsum[15];
        __syncthreads();
    }
    if (t == 0) row_ptr[NN] = carry;
}

__global__ void k_fill(const int* __restrict__ src, const int* __restrict__ dst,
                       const int* __restrict__ row_ptr, int* __restrict__ fillc,
                       int* __restrict__ csr) {
    int e = blockIdx.x * blockDim.x + threadIdx.x;
    if (e < NE) {
        int d = dst[e];
        int pos = row_ptr[d] + atomicAdd(&fillc[d], 1);
        csr[pos] = src[e];
    }
}

// ---------------- mean aggregation: one wave per node ----------------

__global__ __launch_bounds__(256) void k_aggr(const float* __restrict__ x,
        const int* __restrict__ row_ptr, const int* __restrict__ csr,
        float* __restrict__ aggr) {
    int node = blockIdx.x * 4 + (threadIdx.x >> 6);
    int lane = threadIdx.x & 63;
    if (node >= NN) return;
    int r0 = row_ptr[node], r1 = row_ptr[node + 1];
    const float2* xf = (const float2*)x;
    float2 a0 = make_float2(0.f, 0.f), a1 = make_float2(0.f, 0.f);
    int j = r0;
    for (; j + 1 < r1; j += 2) {
        int s0 = csr[j], s1 = csr[j + 1];
        float2 v0 = xf[(size_t)s0 * 64 + lane];
        float2 v1 = xf[(size_t)s1 * 64 + lane];
        a0.x += v0.x; a0.y += v0.y;
        a1.x += v1.x; a1.y += v1.y;
    }
    if (j < r1) {
        int s0 = csr[j];
        float2 v0 = xf[(size_t)s0 * 64 + lane];
        a0.x += v0.x; a0.y += v0.y;
    }
    int d = r1 - r0;
    float sc = d > 0 ? 1.0f / (float)d : 1.0f;
    ((float2*)aggr)[(size_t)node * 64 + lane] =
        make_float2((a0.x + a1.x) * sc, (a0.y + a1.y) * sc);
}

// ---------------- fused multi-input GEMM + bias + relu (+ BN stats) -------
// out[n,o] = relu( sum_p sum_k Ap[n,k] * Wp[o*wstride + k] + bias[o] )
// Tile: 128 nodes x 128 outs per block, 256 threads, 8x8 micro-tile, BK=32.

template<int P, bool STATS>
__global__ __launch_bounds__(256, 2) void k_gemm(
    const float* __restrict__ A0, const float* __restrict__ A1, const float* __restrict__ A2,
    const float* __restrict__ W0, const float* __restrict__ W1, const float* __restrict__ W2,
    int wstride, const float* __restrict__ bias,
    float* __restrict__ out, float* __restrict__ bn_sums)
{
    __shared__ __align__(16) float At[P][32][132];  // [k][n], pitch 132 (16B-aligned rows, 2-way-max write conflicts)
    __shared__ __align__(16) float Wt[P][32][132];  // [k][o]
    __shared__ float bns[128], bnq[128];

    const int tid = threadIdx.x;
    const int tx = tid & 15, ty = tid >> 4;
    const int o0 = tx * 8, n0g = ty * 8;
    const int bn0 = blockIdx.x * 128;

    const float* Ap[3] = {A0, A1, A2};
    const float* Wp[3] = {W0, W1, W2};

    if (STATS && tid < 128) { bns[tid] = 0.f; bnq[tid] = 0.f; }

    float acc[8][8];
    #pragma unroll
    for (int i = 0; i < 8; ++i)
        #pragma unroll
        for (int j = 0; j < 8; ++j) acc[i][j] = 0.f;

    for (int kt = 0; kt < 4; ++kt) {
        const int kslab = kt * 32;
        if (kt) __syncthreads();
        // ---- stage A (transposed) and W (transposed) into LDS ----
        #pragma unroll
        for (int p = 0; p < P; ++p) {
            #pragma unroll
            for (int i = 0; i < 4; ++i) {
                int f = tid + i * 256;        // 0..1023
                int n = f & 127;
                int k0 = (f >> 7) * 4;
                int gn = bn0 + n;
                float4 va = make_float4(0.f, 0.f, 0.f, 0.f);
                if (gn < NN) va = *(const float4*)&Ap[p][(size_t)gn * CH + kslab + k0];
                At[p][k0 + 0][n] = va.x; At[p][k0 + 1][n] = va.y;
                At[p][k0 + 2][n] = va.z; At[p][k0 + 3][n] = va.w;
                float4 vw = *(const float4*)&Wp[p][(size_t)n * wstride + kslab + k0];
                Wt[p][k0 + 0][n] = vw.x; Wt[p][k0 + 1][n] = vw.y;
                Wt[p][k0 + 2][n] = vw.z; Wt[p][k0 + 3][n] = vw.w;
            }
        }
        __syncthreads();
        // ---- compute ----
        #pragma unroll 4
        for (int kk = 0; kk < 32; ++kk) {
            #pragma unroll
            for (int p = 0; p < P; ++p) {
                float4 fa0 = *(const float4*)&At[p][kk][n0g];
                float4 fa1 = *(const float4*)&At[p][kk][n0g + 4];
                float4 fw0 = *(const float4*)&Wt[p][kk][o0];
                float4 fw1 = *(const float4*)&Wt[p][kk][o0 + 4];
                float as[8]  = {fa0.x, fa0.y, fa0.z, fa0.w, fa1.x, fa1.y, fa1.z, fa1.w};
                float wsv[8] = {fw0.x, fw0.y, fw0.z, fw0.w, fw1.x, fw1.y, fw1.z, fw1.w};
                #pragma unroll
                for (int i = 0; i < 8; ++i)
                    #pragma unroll
                    for (int j = 0; j < 8; ++j)
                        acc[i][j] = fmaf(as[i], wsv[j], acc[i][j]);
            }
        }
    }

    // ---- epilogue: bias + relu + store (+ per-channel BN partial sums) ----
    float bv[8];
    #pragma unroll
    for (int j = 0; j < 8; ++j) bv[j] = bias[o0 + j];

    float s[8], q[8];
    #pragma unroll
    for (int j = 0; j < 8; ++j) { s[j] = 0.f; q[j] = 0.f; }

    #pragma unroll
    for (int i = 0; i < 8; ++i) {
        int gn = bn0 + n0g + i;
        if (gn < NN) {
            float r[8];
            #pragma unroll
            for (int j = 0; j < 8; ++j) {
                float v = acc[i][j] + bv[j];
                v = v > 0.f ? v : 0.f;
                r[j] = v;
                if (STATS) { s[j] += v; q[j] += v * v; }
            }
            float4* orow = (float4*)&out[(size_t)gn * CH + o0];
            orow[0] = make_float4(r[0], r[1], r[2], r[3]);
            orow[1] = make_float4(r[4], r[5], r[6], r[7]);
        }
    }

    if (STATS) {
        #pragma unroll
        for (int j = 0; j < 8; ++j) {
            atomicAdd(&bns[o0 + j], s[j]);
            atomicAdd(&bnq[o0 + j], q[j]);
        }
        __syncthreads();
        if (tid < 128) {
            atomicAdd(&bn_sums[tid], bns[tid]);
            atomicAdd(&bn_sums[128 + tid], bnq[tid]);
        }
    }
}

// ---------------- BN finalize + apply ----------------

__global__ void k_bnfin(const float* __restrict__ bn_sums, const float* __restrict__ g,
                        const float* __restrict__ b, float* __restrict__ ab) {
    int o = threadIdx.x;
    float mu = bn_sums[o] * (1.0f / NN);
    float var = bn_sums[128 + o] * (1.0f / NN) - mu * mu;
    var = var > 0.f ? var : 0.f;
    float rstd = rsqrtf(var + EPSV);
    float a = g[o] * rstd;
    ab[o] = a;
    ab[128 + o] = b[o] - a * mu;
}

__global__ __launch_bounds__(256) void k_bnapply(float* __restrict__ x,
                                                 const float* __restrict__ ab) {
    int i = blockIdx.x * blockDim.x + threadIdx.x;  // float4 index
    if (i >= NN * 32) return;
    int c4 = (i & 31) * 4;
    float4 v = ((float4*)x)[i];
    v.x = ab[c4 + 0] * v.x + ab[128 + c4 + 0];
    v.y = ab[c4 + 1] * v.y + ab[128 + c4 + 1];
    v.z = ab[c4 + 2] * v.z + ab[128 + c4 + 2];
    v.w = ab[c4 + 3] * v.w + ab[128 + c4 + 3];
    ((float4*)x)[i] = v;
}

// ---------------- driver ----------------

extern "C" void kernel_launch(void* const* d_in, const int* in_sizes, int n_in,
                              void* d_out, int out_size, void* d_ws, size_t ws_size,
                              hipStream_t stream) {
    const float* x  = (const float*)d_in[0];
    const int*   ei = (const int*)d_in[1];
    const int* esrc = ei;
    const int* edst = ei + NE;

    const float* Wl[3] = {(const float*)d_in[2],  (const float*)d_in[7],  (const float*)d_in[12]};
    const float* bl[3] = {(const float*)d_in[3],  (const float*)d_in[8],  (const float*)d_in[13]};
    const float* Wr[3] = {(const float*)d_in[4],  (const float*)d_in[9],  (const float*)d_in[14]};
    const float* gg[3] = {(const float*)d_in[5],  (const float*)d_in[10], (const float*)d_in[15]};
    const float* bb[3] = {(const float*)d_in[6],  (const float*)d_in[11], (const float*)d_in[16]};
    const float* Wlin  = (const float*)d_in[17];
    const float* blin  = (const float*)d_in[18];

    float* fo = (float*)d_out;  // also doubles as x3 storage

    float* x1      = (float*)d_ws;
    float* x2      = x1 + (size_t)NN * CH;
    float* aggr    = x2 + (size_t)NN * CH;
    float* bn_sums = aggr + (size_t)NN * CH;
    float* ab      = bn_sums + 256;
    int* row_ptr   = (int*)(ab + 256);
    int* fillc     = row_ptr + NN + 1;
    int* csr       = fillc + NN;

    // ---- CSR build ----
    hipMemsetAsync(fillc, 0, NN * sizeof(int), stream);
    k_hist<<<(NE + 255) / 256, 256, 0, stream>>>(edst, fillc);
    k_scan<<<1, 1024, 0, stream>>>(fillc, row_ptr);
    hipMemsetAsync(fillc, 0, NN * sizeof(int), stream);
    k_fill<<<(NE + 255) / 256, 256, 0, stream>>>(esrc, edst, row_ptr, fillc, csr);

    const int GEMM_GRID = (NN + 127) / 128;  // 391

    const float* ins[3] = {x, x1, x2};
    float* outs[3]      = {x1, x2, fo};
    for (int l = 0; l < 3; ++l) {
        k_aggr<<<(NN + 3) / 4, 256, 0, stream>>>(ins[l], row_ptr, csr, aggr);
        hipMemsetAsync(bn_sums, 0, 256 * sizeof(float), stream);
        k_gemm<2, true><<<GEMM_GRID, 256, 0, stream>>>(aggr, ins[l], nullptr,
            Wl[l], Wr[l], nullptr, CH, bl[l], outs[l], bn_sums);
        k_bnfin<<<1, 128, 0, stream>>>(bn_sums, gg[l], bb[l], ab);
        k_bnapply<<<6250, 256, 0, stream>>>(outs[l], ab);
    }

    // final: relu([x1|x2|x3] @ Wlin.T + blin); x3 lives in d_out, written in place
    // (safe: each block reads only its own 128-row slice before its epilogue store)
    k_gemm<3, false><<<GEMM_GRID, 256, 0, stream>>>(x1, x2, fo,
        Wlin, Wlin + CH, Wlin + 2 * CH, 3 * CH, blin, fo, nullptr);
}

// Round 2
// 409.234 us; speedup vs baseline: 1.6452x; 1.6452x over previous
//
#include <hip/hip_runtime.h>

#define NN 50000
#define NE 800000
#define CH 128
#define EPSV 1e-5f

typedef unsigned short ushort_t;
typedef __attribute__((ext_vector_type(8))) short short8_t;
typedef __attribute__((ext_vector_type(4))) float f32x4;

__device__ inline float bf2f(ushort_t u) {
    union { unsigned int i; float f; } t; t.i = ((unsigned int)u) << 16; return t.f;
}
__device__ inline ushort_t f2bf(float f) {
    union { float f; unsigned int i; } t; t.f = f;
    unsigned int r = t.i + 0x7fff + ((t.i >> 16) & 1);   // round-to-nearest-even
    return (ushort_t)(r >> 16);
}

// ---------------- CSR build (dst-sorted pull aggregation) ----------------

__global__ void k_hist(const int* __restrict__ dst, int* __restrict__ deg) {
    int e = blockIdx.x * blockDim.x + threadIdx.x;
    if (e < NE) atomicAdd(&deg[dst[e]], 1);
}

__global__ void k_scan(const int* __restrict__ deg, int* __restrict__ row_ptr) {
    __shared__ int wsum[16];
    const int t = threadIdx.x;
    const int lane = t & 63;
    const int wid = t >> 6;
    int carry = 0;
    for (int base = 0; base < NN; base += 1024) {
        int i = base + t;
        int v = (i < NN) ? deg[i] : 0;
        int x = v;
        #pragma unroll
        for (int off = 1; off < 64; off <<= 1) {
            int y = __shfl_up(x, off, 64);
            if (lane >= off) x += y;
        }
        if (lane == 63) wsum[wid] = x;
        __syncthreads();
        if (wid == 0 && lane < 16) {
            int s = wsum[lane];
            #pragma unroll
            for (int off = 1; off < 16; off <<= 1) {
                int y = __shfl_up(s, off, 16);
                if (lane >= off) s += y;
            }
            wsum[lane] = s;
        }
        __syncthreads();
        int wbase = (wid > 0) ? wsum[wid - 1] : 0;
        if (i < NN) row_ptr[i] = carry + wbase + x - v;
        carry += wsum[15];
        __syncthreads();
    }
    if (t == 0) row_ptr[NN] = carry;
}

__global__ void k_fill(const int* __restrict__ src, const int* __restrict__ dst,
                       const int* __restrict__ row_ptr, int* __restrict__ fillc,
                       int* __restrict__ csr) {
    int e = blockIdx.x * blockDim.x + threadIdx.x;
    if (e < NE) {
        int d = dst[e];
        int pos = row_ptr[d] + atomicAdd(&fillc[d], 1);
        csr[pos] = src[e];
    }
}

// ---------------- conversions / weight packing ----------------

__global__ __launch_bounds__(256) void k_cvtX(const float* __restrict__ x,
                                              ushort_t* __restrict__ xb) {
    int i = blockIdx.x * 256 + threadIdx.x;      // float4 index
    if (i >= NN * 32) return;
    float4 v = ((const float4*)x)[i];
    ushort4 o;
    o.x = f2bf(v.x); o.y = f2bf(v.y); o.z = f2bf(v.z); o.w = f2bf(v.w);
    ((ushort4*)xb)[i] = o;
}

// pack [Wl | Wr] -> dst[o][256] bf16
__global__ __launch_bounds__(256) void k_pack2(const float* __restrict__ s0,
                                               const float* __restrict__ s1,
                                               ushort_t* __restrict__ dst) {
    int t = blockIdx.x * 256 + threadIdx.x;      // 128*256
    if (t >= 128 * 256) return;
    int o = t >> 8, k = t & 255;
    float v = (k < 128) ? s0[o * 128 + k] : s1[o * 128 + k - 128];
    dst[t] = f2bf(v);
}

__global__ __launch_bounds__(256) void k_pack1(const float* __restrict__ s,
                                               ushort_t* __restrict__ dst, int n) {
    int t = blockIdx.x * 256 + threadIdx.x;
    if (t < n) dst[t] = f2bf(s[t]);
}

// ---------------- mean aggregation: one wave per node (bf16) ----------------

__global__ __launch_bounds__(256) void k_aggr(const ushort_t* __restrict__ x,
        const int* __restrict__ row_ptr, const int* __restrict__ csr,
        ushort_t* __restrict__ aggr) {
    int node = blockIdx.x * 4 + (threadIdx.x >> 6);
    int lane = threadIdx.x & 63;
    if (node >= NN) return;
    int r0 = row_ptr[node], r1 = row_ptr[node + 1];
    const ushort2* xv = (const ushort2*)x;
    float a0x = 0.f, a0y = 0.f, a1x = 0.f, a1y = 0.f;
    int j = r0;
    for (; j + 1 < r1; j += 2) {
        int s0 = csr[j], s1 = csr[j + 1];
        ushort2 v0 = xv[(size_t)s0 * 64 + lane];
        ushort2 v1 = xv[(size_t)s1 * 64 + lane];
        a0x += bf2f(v0.x); a0y += bf2f(v0.y);
        a1x += bf2f(v1.x); a1y += bf2f(v1.y);
    }
    if (j < r1) {
        ushort2 v0 = xv[(size_t)csr[j] * 64 + lane];
        a0x += bf2f(v0.x); a0y += bf2f(v0.y);
    }
    int d = r1 - r0;
    float sc = d > 0 ? 1.0f / (float)d : 1.0f;
    ushort2 o;
    o.x = f2bf((a0x + a1x) * sc);
    o.y = f2bf((a0y + a1y) * sc);
    ((ushort2*)aggr)[(size_t)node * 64 + lane] = o;
}

// ---------------- MFMA GEMM: out = relu([A0|A1|A2] @ Wpack.T + bias) --------
// A logically concatenated along K (NT tiles of 64). Wpack: [128][NT*64] bf16.
// Block: 128 nodes x 128 outs, 4 waves at 64x64. LDS XOR-swizzled (T2) via
// pre-swizzled global source (rule 21): linear dest + c^(row&7) src + swz read.

#define STAGE(buf, t) do {                                                           \
    const ushort_t* Ab_ = (((t) >> 1) == 0) ? A0 : ((((t) >> 1) == 1) ? A1 : A2);    \
    Ab_ += ((t) & 1) * 64;                                                           \
    const ushort_t* Wb_ = W + (t) * 64;                                              \
    _Pragma("unroll")                                                                \
    for (int i_ = 0; i_ < 4; ++i_) {                                                 \
        int f_ = i_ * 256 + tid;                                                     \
        int row_ = f_ >> 3;                                                          \
        int c_ = (f_ & 7) ^ (row_ & 7);                                              \
        int gr_ = bn0 + row_; gr_ = gr_ < NN ? gr_ : NN - 1;                         \
        __builtin_amdgcn_global_load_lds(                                            \
            (const __attribute__((address_space(1))) unsigned int*)(Ab_ + (size_t)gr_ * CH + c_ * 8), \
            (__attribute__((address_space(3))) unsigned int*)(&Abuf[buf][f_ * 8]),   \
            16, 0, 0);                                                               \
        __builtin_amdgcn_global_load_lds(                                            \
            (const __attribute__((address_space(1))) unsigned int*)(Wb_ + (size_t)row_ * (NT * 64) + c_ * 8), \
            (__attribute__((address_space(3))) unsigned int*)(&Wbuf[buf][f_ * 8]),   \
            16, 0, 0);                                                               \
    } } while (0)

template<int NT, bool STATS, bool F32OUT>
__global__ __launch_bounds__(256, 2) void k_mgemm(
    const ushort_t* __restrict__ A0, const ushort_t* __restrict__ A1,
    const ushort_t* __restrict__ A2,
    const ushort_t* __restrict__ W, const float* __restrict__ bias,
    ushort_t* __restrict__ outb, float* __restrict__ outf,
    float* __restrict__ bn_sums)
{
    __shared__ __align__(16) ushort_t Abuf[2][128 * 64];
    __shared__ __align__(16) ushort_t Wbuf[2][128 * 64];
    __shared__ float bns[128], bnq[128];

    const int tid  = threadIdx.x;
    const int lane = tid & 63;
    const int wid  = tid >> 6;
    const int l15  = lane & 15;
    const int lg   = lane >> 4;
    const int wn   = (wid >> 1) * 64;   // wave node-origin within tile
    const int wo   = (wid & 1) * 64;    // wave out-origin within tile
    const int bn0  = blockIdx.x * 128;

    if (STATS && tid < 128) { bns[tid] = 0.f; bnq[tid] = 0.f; }

    f32x4 acc[4][4];
    #pragma unroll
    for (int i = 0; i < 4; ++i)
        #pragma unroll
        for (int j = 0; j < 4; ++j)
            acc[i][j] = (f32x4){0.f, 0.f, 0.f, 0.f};

    STAGE(0, 0);
    asm volatile("s_waitcnt vmcnt(0)");
    __syncthreads();

    #pragma unroll
    for (int t = 0; t < NT; ++t) {
        const int cur = t & 1;
        if (t + 1 < NT) STAGE(cur ^ 1, t + 1);
        #pragma unroll
        for (int s = 0; s < 2; ++s) {
            short8_t af[4], wf[4];
            #pragma unroll
            for (int b = 0; b < 4; ++b) {
                int ra = wn + b * 16 + l15;
                int ca = (s * 4 + lg) ^ (ra & 7);
                af[b] = *(const short8_t*)&Abuf[cur][ra * 64 + ca * 8];
                int rw = wo + b * 16 + l15;
                int cw = (s * 4 + lg) ^ (rw & 7);
                wf[b] = *(const short8_t*)&Wbuf[cur][rw * 64 + cw * 8];
            }
            #pragma unroll
            for (int i = 0; i < 4; ++i)
                #pragma unroll
                for (int j = 0; j < 4; ++j)
                    acc[i][j] = __builtin_amdgcn_mfma_f32_16x16x32_bf16(
                        af[i], wf[j], acc[i][j], 0, 0, 0);
        }
        asm volatile("s_waitcnt vmcnt(0)");
        __syncthreads();
    }

    // epilogue: bias + relu + store (+ BN stats from fp32 acc)
    float bv[4];
    #pragma unroll
    for (int j = 0; j < 4; ++j) bv[j] = bias[wo + j * 16 + l15];

    float sum[4] = {0.f, 0.f, 0.f, 0.f}, sq[4] = {0.f, 0.f, 0.f, 0.f};

    #pragma unroll
    for (int i = 0; i < 4; ++i) {
        #pragma unroll
        for (int r = 0; r < 4; ++r) {
            int gn = bn0 + wn + i * 16 + lg * 4 + r;
            bool ok = gn < NN;
            #pragma unroll
            for (int j = 0; j < 4; ++j) {
                int o = wo + j * 16 + l15;
                float v = acc[i][j][r] + bv[j];
                v = fmaxf(v, 0.f);
                if (ok) {
                    if (F32OUT) outf[(size_t)gn * CH + o] = v;
                    else        outb[(size_t)gn * CH + o] = f2bf(v);
                    if (STATS) { sum[j] += v; sq[j] += v * v; }
                }
            }
        }
    }

    if (STATS) {
        #pragma unroll
        for (int j = 0; j < 4; ++j) {
            float ss = sum[j], qq = sq[j];
            ss += __shfl_xor(ss, 16); qq += __shfl_xor(qq, 16);
            ss += __shfl_xor(ss, 32); qq += __shfl_xor(qq, 32);
            if (lg == 0) {
                atomicAdd(&bns[wo + j * 16 + l15], ss);
                atomicAdd(&bnq[wo + j * 16 + l15], qq);
            }
        }
        __syncthreads();
        if (tid < 128) {
            atomicAdd(&bn_sums[tid], bns[tid]);
            atomicAdd(&bn_sums[128 + tid], bnq[tid]);
        }
    }
}

// ---------------- BN finalize + in-place bf16 apply ----------------

__global__ void k_bnfin(const float* __restrict__ bn_sums, const float* __restrict__ g,
                        const float* __restrict__ b, float* __restrict__ ab) {
    int o = threadIdx.x;
    float mu = bn_sums[o] * (1.0f / NN);
    float var = bn_sums[128 + o] * (1.0f / NN) - mu * mu;
    var = var > 0.f ? var : 0.f;
    float rstd = rsqrtf(var + EPSV);
    float a = g[o] * rstd;
    ab[o] = a;
    ab[128 + o] = b[o] - a * mu;
}

__global__ __launch_bounds__(256) void k_bnapply(ushort_t* __restrict__ xp,
                                                 const float* __restrict__ ab) {
    int i = blockIdx.x * 256 + threadIdx.x;      // ushort4 index
    if (i >= NN * 32) return;
    int c4 = (i & 31) * 4;
    ushort4 v = ((ushort4*)xp)[i];
    v.x = f2bf(bf2f(v.x) * ab[c4 + 0] + ab[128 + c4 + 0]);
    v.y = f2bf(bf2f(v.y) * ab[c4 + 1] + ab[128 + c4 + 1]);
    v.z = f2bf(bf2f(v.z) * ab[c4 + 2] + ab[128 + c4 + 2]);
    v.w = f2bf(bf2f(v.w) * ab[c4 + 3] + ab[128 + c4 + 3]);
    ((ushort4*)xp)[i] = v;
}

// ---------------- driver ----------------

extern "C" void kernel_launch(void* const* d_in, const int* in_sizes, int n_in,
                              void* d_out, int out_size, void* d_ws, size_t ws_size,
                              hipStream_t stream) {
    const float* x  = (const float*)d_in[0];
    const int*   ei = (const int*)d_in[1];
    const int* esrc = ei;
    const int* edst = ei + NE;

    const float* Wl[3] = {(const float*)d_in[2],  (const float*)d_in[7],  (const float*)d_in[12]};
    const float* bl[3] = {(const float*)d_in[3],  (const float*)d_in[8],  (const float*)d_in[13]};
    const float* Wr[3] = {(const float*)d_in[4],  (const float*)d_in[9],  (const float*)d_in[14]};
    const float* gg[3] = {(const float*)d_in[5],  (const float*)d_in[10], (const float*)d_in[15]};
    const float* bb[3] = {(const float*)d_in[6],  (const float*)d_in[11], (const float*)d_in[16]};
    const float* Wlin  = (const float*)d_in[17];
    const float* blin  = (const float*)d_in[18];

    float* fo = (float*)d_out;

    const size_t NC = (size_t)NN * CH;
    ushort_t* xb     = (ushort_t*)d_ws;
    ushort_t* x1b    = xb + NC;
    ushort_t* x2b    = x1b + NC;
    ushort_t* x3b    = x2b + NC;
    ushort_t* aggr_b = x3b + NC;
    ushort_t* Wp1    = aggr_b + NC;            // 128*256 each
    ushort_t* Wp2    = Wp1 + 128 * 256;
    ushort_t* Wp3    = Wp2 + 128 * 256;
    ushort_t* WpF    = Wp3 + 128 * 256;        // 128*384
    float* bn_sums   = (float*)(WpF + 128 * 384);
    float* ab        = bn_sums + 256;
    int* row_ptr     = (int*)(ab + 256);
    int* fillc       = row_ptr + NN + 1;
    int* csr         = fillc + NN;

    // ---- CSR build ----
    hipMemsetAsync(fillc, 0, NN * sizeof(int), stream);
    k_hist<<<(NE + 255) / 256, 256, 0, stream>>>(edst, fillc);
    k_scan<<<1, 1024, 0, stream>>>(fillc, row_ptr);
    hipMemsetAsync(fillc, 0, NN * sizeof(int), stream);
    k_fill<<<(NE + 255) / 256, 256, 0, stream>>>(esrc, edst, row_ptr, fillc, csr);

    // ---- conversions ----
    k_cvtX<<<(NN * 32 + 255) / 256, 256, 0, stream>>>(x, xb);
    k_pack2<<<128, 256, 0, stream>>>(Wl[0], Wr[0], Wp1);
    k_pack2<<<128, 256, 0, stream>>>(Wl[1], Wr[1], Wp2);
    k_pack2<<<128, 256, 0, stream>>>(Wl[2], Wr[2], Wp3);
    k_pack1<<<192, 256, 0, stream>>>(Wlin, WpF, 128 * 384);

    const int GEMM_GRID = (NN + 127) / 128;    // 391
    ushort_t* Wps[3]  = {Wp1, Wp2, Wp3};
    const ushort_t* ins[3]  = {xb, x1b, x2b};
    ushort_t*       outs[3] = {x1b, x2b, x3b};

    for (int l = 0; l < 3; ++l) {
        k_aggr<<<(NN + 3) / 4, 256, 0, stream>>>(ins[l], row_ptr, csr, aggr_b);
        hipMemsetAsync(bn_sums, 0, 256 * sizeof(float), stream);
        k_mgemm<4, true, false><<<GEMM_GRID, 256, 0, stream>>>(
            aggr_b, ins[l], nullptr, Wps[l], bl[l], outs[l], nullptr, bn_sums);
        k_bnfin<<<1, 128, 0, stream>>>(bn_sums, gg[l], bb[l], ab);
        k_bnapply<<<(NN * 32 + 255) / 256, 256, 0, stream>>>(outs[l], ab);
    }

    // final: relu([x1|x2|x3] @ Wlin.T + blin) -> fp32 d_out
    k_mgemm<6, false, true><<<GEMM_GRID, 256, 0, stream>>>(
        x1b, x2b, x3b, WpF, blin, nullptr, fo, nullptr);
}

// Round 3
// 373.313 us; speedup vs baseline: 1.8035x; 1.0962x over previous
//
#include <hip/hip_runtime.h>

#define NN 50000
#define NE 800000
#define CH 128
#define EPSV 1e-5f

typedef unsigned short ushort_t;
typedef __attribute__((ext_vector_type(8))) short short8_t;
typedef __attribute__((ext_vector_type(8))) unsigned short u16x8;
typedef __attribute__((ext_vector_type(4))) float f32x4;

__device__ inline float bf2f(ushort_t u) {
    union { unsigned int i; float f; } t; t.i = ((unsigned int)u) << 16; return t.f;
}
__device__ inline ushort_t f2bf(float f) {
    union { float f; unsigned int i; } t; t.f = f;
    unsigned int r = t.i + 0x7fff + ((t.i >> 16) & 1);   // round-to-nearest-even
    return (ushort_t)(r >> 16);
}

// ---------------- CSR build (dst-sorted pull aggregation) ----------------

__global__ void k_hist(const int* __restrict__ dst, int* __restrict__ deg) {
    int e = blockIdx.x * blockDim.x + threadIdx.x;
    if (e < NE) atomicAdd(&deg[dst[e]], 1);
}

__global__ void k_scan(const int* __restrict__ deg, int* __restrict__ row_ptr) {
    __shared__ int wsum[16];
    const int t = threadIdx.x;
    const int lane = t & 63;
    const int wid = t >> 6;
    int carry = 0;
    for (int base = 0; base < NN; base += 1024) {
        int i = base + t;
        int v = (i < NN) ? deg[i] : 0;
        int x = v;
        #pragma unroll
        for (int off = 1; off < 64; off <<= 1) {
            int y = __shfl_up(x, off, 64);
            if (lane >= off) x += y;
        }
        if (lane == 63) wsum[wid] = x;
        __syncthreads();
        if (wid == 0 && lane < 16) {
            int s = wsum[lane];
            #pragma unroll
            for (int off = 1; off < 16; off <<= 1) {
                int y = __shfl_up(s, off, 16);
                if (lane >= off) s += y;
            }
            wsum[lane] = s;
        }
        __syncthreads();
        int wbase = (wid > 0) ? wsum[wid - 1] : 0;
        if (i < NN) row_ptr[i] = carry + wbase + x - v;
        carry += wsum[15];
        __syncthreads();
    }
    if (t == 0) row_ptr[NN] = carry;
}

__global__ void k_fill(const int* __restrict__ src, const int* __restrict__ dst,
                       const int* __restrict__ row_ptr, int* __restrict__ fillc,
                       int* __restrict__ csr) {
    int e = blockIdx.x * blockDim.x + threadIdx.x;
    if (e < NE) {
        int d = dst[e];
        int pos = row_ptr[d] + atomicAdd(&fillc[d], 1);
        csr[pos] = src[e];
    }
}

// ---------------- conversions / weight packing ----------------

__global__ __launch_bounds__(256) void k_cvtX(const float* __restrict__ x,
                                              ushort_t* __restrict__ xb) {
    int i = blockIdx.x * 256 + threadIdx.x;      // float4 index
    if (i >= NN * 32) return;
    float4 v = ((const float4*)x)[i];
    ushort4 o;
    o.x = f2bf(v.x); o.y = f2bf(v.y); o.z = f2bf(v.z); o.w = f2bf(v.w);
    ((ushort4*)xb)[i] = o;
}

// plain pack [Wl | Wr] -> dst[o][256] bf16 (layer 1, no BN fold)
__global__ __launch_bounds__(256) void k_pack2(const float* __restrict__ s0,
                                               const float* __restrict__ s1,
                                               ushort_t* __restrict__ dst) {
    int t = blockIdx.x * 256 + threadIdx.x;      // 128*256
    if (t >= 128 * 256) return;
    int o = t >> 8, k = t & 255;
    float v = (k < 128) ? s0[o * 128 + k] : s1[o * 128 + k - 128];
    dst[t] = f2bf(v);
}

// BN-folded pack for layer l+1: Wp = [Wl | Wr * a], bias = bl + Wr @ c
// ab = {a[128], c[128]} from k_bnfin of layer l. 128 blocks x 128 threads.
__global__ void k_packfold(const float* __restrict__ Wl, const float* __restrict__ Wr,
                           const float* __restrict__ ab, const float* __restrict__ bl,
                           ushort_t* __restrict__ Wp, float* __restrict__ bias) {
    __shared__ float red[128];
    int o = blockIdx.x;
    int k = threadIdx.x;
    float wr = Wr[o * 128 + k];
    Wp[o * 256 + k]       = f2bf(Wl[o * 128 + k]);
    Wp[o * 256 + 128 + k] = f2bf(wr * ab[k]);
    red[k] = wr * ab[128 + k];
    __syncthreads();
    for (int s = 64; s > 0; s >>= 1) {
        if (k < s) red[k] += red[k + s];
        __syncthreads();
    }
    if (k == 0) bias[o] = bl[o] + red[0];
}

// BN-folded pack for final concat GEMM: Wp[o][384], bias = blin + sum_i Wlin_i @ c_i
__global__ void k_packfoldF(const float* __restrict__ Wlin,
                            const float* __restrict__ ab1, const float* __restrict__ ab2,
                            const float* __restrict__ ab3, const float* __restrict__ blin,
                            ushort_t* __restrict__ Wp, float* __restrict__ bias) {
    __shared__ float red[128];
    int o = blockIdx.x;
    int k = threadIdx.x;
    const float* abs_[3] = {ab1, ab2, ab3};
    float dot = 0.f;
    #pragma unroll
    for (int i = 0; i < 3; ++i) {
        float w = Wlin[o * 384 + i * 128 + k];
        Wp[o * 384 + i * 128 + k] = f2bf(w * abs_[i][k]);
        dot += w * abs_[i][128 + k];
    }
    red[k] = dot;
    __syncthreads();
    for (int s = 64; s > 0; s >>= 1) {
        if (k < s) red[k] += red[k + s];
        __syncthreads();
    }
    if (k == 0) bias[o] = blin[o] + red[0];
}

// ---------------- mean aggregation: one wave per node, 16B/lane gather ------
// 16 lanes cover one 256B row; one wave-instr gathers 4 edges (1KB). Unroll x2.
// FOLD: output = deg>0 ? a * mean(y) + c : 0   (BN affine folded in).

template<bool FOLD>
__global__ __launch_bounds__(256) void k_aggr(const ushort_t* __restrict__ x,
        const int* __restrict__ row_ptr, const int* __restrict__ csr,
        const float* __restrict__ ab, ushort_t* __restrict__ aggr) {
    const int node = blockIdx.x * 4 + (threadIdx.x >> 6);   // grid = NN/4 exact
    const int lane = threadIdx.x & 63;
    const int l4 = lane & 15;        // channel group: ch l4*8 .. l4*8+7
    const int q  = lane >> 4;        // edge phase 0..3
    const int r0 = row_ptr[node], r1 = row_ptr[node + 1];
    const int d = r1 - r0;

    float accA[8] = {0, 0, 0, 0, 0, 0, 0, 0};
    float accB[8] = {0, 0, 0, 0, 0, 0, 0, 0};

    int j = r0 + q;
    for (; j + 4 < r1; j += 8) {     // 8 edges per wave-iter (2 per quarter)
        int s0 = csr[j], s1 = csr[j + 4];
        u16x8 v0 = *(const u16x8*)&x[(size_t)s0 * CH + l4 * 8];
        u16x8 v1 = *(const u16x8*)&x[(size_t)s1 * CH + l4 * 8];
        #pragma unroll
        for (int i = 0; i < 8; ++i) {
            accA[i] += bf2f(v0[i]);
            accB[i] += bf2f(v1[i]);
        }
    }
    for (; j < r1; j += 4) {
        int s0 = csr[j];
        u16x8 v0 = *(const u16x8*)&x[(size_t)s0 * CH + l4 * 8];
        #pragma unroll
        for (int i = 0; i < 8; ++i) accA[i] += bf2f(v0[i]);
    }

    const float sc = d > 0 ? 1.0f / (float)d : 0.0f;
    #pragma unroll
    for (int i = 0; i < 8; ++i) {
        float s = accA[i] + accB[i];
        s += __shfl_xor(s, 16);
        s += __shfl_xor(s, 32);
        accA[i] = s * sc;
    }

    if (q == 0) {
        u16x8 ov;
        #pragma unroll
        for (int i = 0; i < 8; ++i) {
            float v = accA[i];
            if (FOLD) v = d > 0 ? fmaf(v, ab[l4 * 8 + i], ab[128 + l4 * 8 + i]) : 0.f;
            ov[i] = f2bf(v);
        }
        *(u16x8*)&aggr[(size_t)node * CH + l4 * 8] = ov;
    }
}

// ---------------- MFMA GEMM: out = relu([A0|A1|A2] @ Wpack.T + bias) --------
// A logically concatenated along K (NT tiles of 64). Wpack: [128][NT*64] bf16.
// Block: 128 nodes x 128 outs, 4 waves at 64x64. LDS XOR-swizzled (T2) via
// pre-swizzled global source (rule 21): linear dest + c^(row&7) src + swz read.

#define STAGE(buf, t) do {                                                           \
    const ushort_t* Ab_ = (((t) >> 1) == 0) ? A0 : ((((t) >> 1) == 1) ? A1 : A2);    \
    Ab_ += ((t) & 1) * 64;                                                           \
    const ushort_t* Wb_ = W + (t) * 64;                                              \
    _Pragma("unroll")                                                                \
    for (int i_ = 0; i_ < 4; ++i_) {                                                 \
        int f_ = i_ * 256 + tid;                                                     \
        int row_ = f_ >> 3;                                                          \
        int c_ = (f_ & 7) ^ (row_ & 7);                                              \
        int gr_ = bn0 + row_; gr_ = gr_ < NN ? gr_ : NN - 1;                         \
        __builtin_amdgcn_global_load_lds(                                            \
            (const __attribute__((address_space(1))) unsigned int*)(Ab_ + (size_t)gr_ * CH + c_ * 8), \
            (__attribute__((address_space(3))) unsigned int*)(&Abuf[buf][f_ * 8]),   \
            16, 0, 0);                                                               \
        __builtin_amdgcn_global_load_lds(                                            \
            (const __attribute__((address_space(1))) unsigned int*)(Wb_ + (size_t)row_ * (NT * 64) + c_ * 8), \
            (__attribute__((address_space(3))) unsigned int*)(&Wbuf[buf][f_ * 8]),   \
            16, 0, 0);                                                               \
    } } while (0)

template<int NT, bool STATS, bool F32OUT>
__global__ __launch_bounds__(256, 2) void k_mgemm(
    const ushort_t* __restrict__ A0, const ushort_t* __restrict__ A1,
    const ushort_t* __restrict__ A2,
    const ushort_t* __restrict__ W, const float* __restrict__ bias,
    ushort_t* __restrict__ outb, float* __restrict__ outf,
    float* __restrict__ bn_sums)
{
    __shared__ __align__(16) ushort_t Abuf[2][128 * 64];
    __shared__ __align__(16) ushort_t Wbuf[2][128 * 64];
    __shared__ float bns[128], bnq[128];

    const int tid  = threadIdx.x;
    const int lane = tid & 63;
    const int wid  = tid >> 6;
    const int l15  = lane & 15;
    const int lg   = lane >> 4;
    const int wn   = (wid >> 1) * 64;   // wave node-origin within tile
    const int wo   = (wid & 1) * 64;    // wave out-origin within tile
    const int bn0  = blockIdx.x * 128;

    if (STATS && tid < 128) { bns[tid] = 0.f; bnq[tid] = 0.f; }

    f32x4 acc[4][4];
    #pragma unroll
    for (int i = 0; i < 4; ++i)
        #pragma unroll
        for (int j = 0; j < 4; ++j)
            acc[i][j] = (f32x4){0.f, 0.f, 0.f, 0.f};

    STAGE(0, 0);
    asm volatile("s_waitcnt vmcnt(0)");
    __syncthreads();

    #pragma unroll
    for (int t = 0; t < NT; ++t) {
        const int cur = t & 1;
        if (t + 1 < NT) STAGE(cur ^ 1, t + 1);
        #pragma unroll
        for (int s = 0; s < 2; ++s) {
            short8_t af[4], wf[4];
            #pragma unroll
            for (int b = 0; b < 4; ++b) {
                int ra = wn + b * 16 + l15;
                int ca = (s * 4 + lg) ^ (ra & 7);
                af[b] = *(const short8_t*)&Abuf[cur][ra * 64 + ca * 8];
                int rw = wo + b * 16 + l15;
                int cw = (s * 4 + lg) ^ (rw & 7);
                wf[b] = *(const short8_t*)&Wbuf[cur][rw * 64 + cw * 8];
            }
            #pragma unroll
            for (int i = 0; i < 4; ++i)
                #pragma unroll
                for (int j = 0; j < 4; ++j)
                    acc[i][j] = __builtin_amdgcn_mfma_f32_16x16x32_bf16(
                        af[i], wf[j], acc[i][j], 0, 0, 0);
        }
        asm volatile("s_waitcnt vmcnt(0)");
        __syncthreads();
    }

    // epilogue: bias + relu + store (+ BN stats from fp32 acc)
    float bv[4];
    #pragma unroll
    for (int j = 0; j < 4; ++j) bv[j] = bias[wo + j * 16 + l15];

    float sum[4] = {0.f, 0.f, 0.f, 0.f}, sq[4] = {0.f, 0.f, 0.f, 0.f};

    #pragma unroll
    for (int i = 0; i < 4; ++i) {
        #pragma unroll
        for (int r = 0; r < 4; ++r) {
            int gn = bn0 + wn + i * 16 + lg * 4 + r;
            bool ok = gn < NN;
            #pragma unroll
            for (int j = 0; j < 4; ++j) {
                int o = wo + j * 16 + l15;
                float v = acc[i][j][r] + bv[j];
                v = fmaxf(v, 0.f);
                if (ok) {
                    if (F32OUT) outf[(size_t)gn * CH + o] = v;
                    else        outb[(size_t)gn * CH + o] = f2bf(v);
                    if (STATS) { sum[j] += v; sq[j] += v * v; }
                }
            }
        }
    }

    if (STATS) {
        #pragma unroll
        for (int j = 0; j < 4; ++j) {
            float ss = sum[j], qq = sq[j];
            ss += __shfl_xor(ss, 16); qq += __shfl_xor(qq, 16);
            ss += __shfl_xor(ss, 32); qq += __shfl_xor(qq, 32);
            if (lg == 0) {
                atomicAdd(&bns[wo + j * 16 + l15], ss);
                atomicAdd(&bnq[wo + j * 16 + l15], qq);
            }
        }
        __syncthreads();
        if (tid < 128) {
            atomicAdd(&bn_sums[tid], bns[tid]);
            atomicAdd(&bn_sums[128 + tid], bnq[tid]);
        }
    }
}

// ---------------- BN finalize: ab = {a = g*rstd, c = b - a*mu} ----------------

__global__ void k_bnfin(const float* __restrict__ bn_sums, const float* __restrict__ g,
                        const float* __restrict__ b, float* __restrict__ ab) {
    int o = threadIdx.x;
    float mu = bn_sums[o] * (1.0f / NN);
    float var = bn_sums[128 + o] * (1.0f / NN) - mu * mu;
    var = var > 0.f ? var : 0.f;
    float rstd = rsqrtf(var + EPSV);
    float a = g[o] * rstd;
    ab[o] = a;
    ab[128 + o] = b[o] - a * mu;
}

// ---------------- driver ----------------

extern "C" void kernel_launch(void* const* d_in, const int* in_sizes, int n_in,
                              void* d_out, int out_size, void* d_ws, size_t ws_size,
                              hipStream_t stream) {
    const float* x  = (const float*)d_in[0];
    const int*   ei = (const int*)d_in[1];
    const int* esrc = ei;
    const int* edst = ei + NE;

    const float* Wl[3] = {(const float*)d_in[2],  (const float*)d_in[7],  (const float*)d_in[12]};
    const float* bl[3] = {(const float*)d_in[3],  (const float*)d_in[8],  (const float*)d_in[13]};
    const float* Wr[3] = {(const float*)d_in[4],  (const float*)d_in[9],  (const float*)d_in[14]};
    const float* gg[3] = {(const float*)d_in[5],  (const float*)d_in[10], (const float*)d_in[15]};
    const float* bb[3] = {(const float*)d_in[6],  (const float*)d_in[11], (const float*)d_in[16]};
    const float* Wlin  = (const float*)d_in[17];
    const float* blin  = (const float*)d_in[18];

    float* fo = (float*)d_out;

    const size_t NC = (size_t)NN * CH;
    ushort_t* xb     = (ushort_t*)d_ws;
    ushort_t* y1b    = xb + NC;
    ushort_t* y2b    = y1b + NC;
    ushort_t* y3b    = y2b + NC;
    ushort_t* aggr_b = y3b + NC;
    ushort_t* Wp1    = aggr_b + NC;            // [128][256]
    ushort_t* Wp2    = Wp1 + 128 * 256;
    ushort_t* Wp3    = Wp2 + 128 * 256;
    ushort_t* WpF    = Wp3 + 128 * 256;        // [128][384]
    float* bias2     = (float*)(WpF + 128 * 384);
    float* bias3     = bias2 + 128;
    float* biasF     = bias3 + 128;
    float* bn_sums   = biasF + 128;            // 3 x 256
    float* ab        = bn_sums + 768;          // 3 x 256
    int* row_ptr     = (int*)(ab + 768);
    int* fillc       = row_ptr + NN + 1;
    int* csr         = fillc + NN;

    // ---- CSR build ----
    hipMemsetAsync(fillc, 0, NN * sizeof(int), stream);
    k_hist<<<(NE + 255) / 256, 256, 0, stream>>>(edst, fillc);
    k_scan<<<1, 1024, 0, stream>>>(fillc, row_ptr);
    hipMemsetAsync(fillc, 0, NN * sizeof(int), stream);
    k_fill<<<(NE + 255) / 256, 256, 0, stream>>>(esrc, edst, row_ptr, fillc, csr);

    // ---- conversions / static packs / stats zero ----
    k_cvtX<<<(NN * 32 + 255) / 256, 256, 0, stream>>>(x, xb);
    k_pack2<<<128, 256, 0, stream>>>(Wl[0], Wr[0], Wp1);
    hipMemsetAsync(bn_sums, 0, 768 * sizeof(float), stream);

    const int GEMM_GRID = (NN + 127) / 128;    // 391

    // ---- layer 1 ----
    k_aggr<false><<<NN / 4, 256, 0, stream>>>(xb, row_ptr, csr, nullptr, aggr_b);
    k_mgemm<4, true, false><<<GEMM_GRID, 256, 0, stream>>>(
        aggr_b, xb, nullptr, Wp1, bl[0], y1b, nullptr, bn_sums);
    k_bnfin<<<1, 128, 0, stream>>>(bn_sums, gg[0], bb[0], ab);
    k_packfold<<<128, 128, 0, stream>>>(Wl[1], Wr[1], ab, bl[1], Wp2, bias2);

    // ---- layer 2 ----
    k_aggr<true><<<NN / 4, 256, 0, stream>>>(y1b, row_ptr, csr, ab, aggr_b);
    k_mgemm<4, true, false><<<GEMM_GRID, 256, 0, stream>>>(
        aggr_b, y1b, nullptr, Wp2, bias2, y2b, nullptr, bn_sums + 256);
    k_bnfin<<<1, 128, 0, stream>>>(bn_sums + 256, gg[1], bb[1], ab + 256);
    k_packfold<<<128, 128, 0, stream>>>(Wl[2], Wr[2], ab + 256, bl[2], Wp3, bias3);

    // ---- layer 3 ----
    k_aggr<true><<<NN / 4, 256, 0, stream>>>(y2b, row_ptr, csr, ab + 256, aggr_b);
    k_mgemm<4, true, false><<<GEMM_GRID, 256, 0, stream>>>(
        aggr_b, y2b, nullptr, Wp3, bias3, y3b, nullptr, bn_sums + 512);
    k_bnfin<<<1, 128, 0, stream>>>(bn_sums + 512, gg[2], bb[2], ab + 512);
    k_packfoldF<<<128, 128, 0, stream>>>(Wlin, ab, ab + 256, ab + 512, blin, WpF, biasF);

    // ---- final: relu([x1|x2|x3] @ Wlin.T + blin) with BN folded into WpF ----
    k_mgemm<6, false, true><<<GEMM_GRID, 256, 0, stream>>>(
        y1b, y2b, y3b, WpF, biasF, nullptr, fo, nullptr);
}

// Round 4
// 367.856 us; speedup vs baseline: 1.8303x; 1.0148x over previous
//
#include <hip/hip_runtime.h>

#define NN 50000
#define NE 800000
#define CH 128
#define EPSV 1e-5f
#define NPASS 4
#define PRANGE 12500

typedef unsigned short ushort_t;
typedef __attribute__((ext_vector_type(8))) short short8_t;
typedef __attribute__((ext_vector_type(8))) unsigned short u16x8;
typedef __attribute__((ext_vector_type(4))) float f32x4;

__device__ inline float bf2f(ushort_t u) {
    union { unsigned int i; float f; } t; t.i = ((unsigned int)u) << 16; return t.f;
}
__device__ inline ushort_t f2bf(float f) {
    union { float f; unsigned int i; } t; t.f = f;
    unsigned int r = t.i + 0x7fff + ((t.i >> 16) & 1);   // round-to-nearest-even
    return (ushort_t)(r >> 16);
}

// ---------------- CSR build: bucketed by dst range (write-locality) ---------

__global__ void k_histp(const int* __restrict__ dst, int* __restrict__ deg,
                        int lo, int hi) {
    int e = blockIdx.x * 256 + threadIdx.x;
    if (e < NE) {
        int d = dst[e];
        if (d >= lo && d < hi) atomicAdd(&deg[d], 1);
    }
}

__global__ void k_scan(const int* __restrict__ deg, int* __restrict__ row_ptr) {
    __shared__ int wsum[16];
    const int t = threadIdx.x;
    const int lane = t & 63;
    const int wid = t >> 6;
    int carry = 0;
    for (int base = 0; base < NN; base += 1024) {
        int i = base + t;
        int v = (i < NN) ? deg[i] : 0;
        int x = v;
        #pragma unroll
        for (int off = 1; off < 64; off <<= 1) {
            int y = __shfl_up(x, off, 64);
            if (lane >= off) x += y;
        }
        if (lane == 63) wsum[wid] = x;
        __syncthreads();
        if (wid == 0 && lane < 16) {
            int s = wsum[lane];
            #pragma unroll
            for (int off = 1; off < 16; off <<= 1) {
                int y = __shfl_up(s, off, 16);
                if (lane >= off) s += y;
            }
            wsum[lane] = s;
        }
        __syncthreads();
        int wbase = (wid > 0) ? wsum[wid - 1] : 0;
        if (i < NN) row_ptr[i] = carry + wbase + x - v;
        carry += wsum[15];
        __syncthreads();
    }
    if (t == 0) row_ptr[NN] = carry;
}

__global__ void k_fillp(const int* __restrict__ src, const int* __restrict__ dst,
                        const int* __restrict__ row_ptr, int* __restrict__ fillc,
                        int* __restrict__ csr, int lo, int hi) {
    int e = blockIdx.x * 256 + threadIdx.x;
    if (e < NE) {
        int d = dst[e];
        int s = src[e];
        if (d >= lo && d < hi) {
            int pos = row_ptr[d] + atomicAdd(&fillc[d], 1);
            csr[pos] = s;
        }
    }
}

// ---------------- conversions / weight packing ----------------

__global__ __launch_bounds__(256) void k_cvtX(const float* __restrict__ x,
                                              ushort_t* __restrict__ xb) {
    int i = blockIdx.x * 256 + threadIdx.x;      // float4 index
    if (i >= NN * 32) return;
    float4 v = ((const float4*)x)[i];
    ushort4 o;
    o.x = f2bf(v.x); o.y = f2bf(v.y); o.z = f2bf(v.z); o.w = f2bf(v.w);
    ((ushort4*)xb)[i] = o;
}

// plain pack [Wl | Wr] -> dst[o][256] bf16 (layer 1, no BN fold)
__global__ __launch_bounds__(256) void k_pack2(const float* __restrict__ s0,
                                               const float* __restrict__ s1,
                                               ushort_t* __restrict__ dst) {
    int t = blockIdx.x * 256 + threadIdx.x;      // 128*256
    if (t >= 128 * 256) return;
    int o = t >> 8, k = t & 255;
    float v = (k < 128) ? s0[o * 128 + k] : s1[o * 128 + k - 128];
    dst[t] = f2bf(v);
}

// BN-folded pack for layer l+1: Wp = [Wl | Wr * a], bias = bl + Wr @ c
__global__ void k_packfold(const float* __restrict__ Wl, const float* __restrict__ Wr,
                           const float* __restrict__ ab, const float* __restrict__ bl,
                           ushort_t* __restrict__ Wp, float* __restrict__ bias) {
    __shared__ float red[128];
    int o = blockIdx.x;
    int k = threadIdx.x;
    float wr = Wr[o * 128 + k];
    Wp[o * 256 + k]       = f2bf(Wl[o * 128 + k]);
    Wp[o * 256 + 128 + k] = f2bf(wr * ab[k]);
    red[k] = wr * ab[128 + k];
    __syncthreads();
    for (int s = 64; s > 0; s >>= 1) {
        if (k < s) red[k] += red[k + s];
        __syncthreads();
    }
    if (k == 0) bias[o] = bl[o] + red[0];
}

// BN-folded pack for final concat GEMM
__global__ void k_packfoldF(const float* __restrict__ Wlin,
                            const float* __restrict__ ab1, const float* __restrict__ ab2,
                            const float* __restrict__ ab3, const float* __restrict__ blin,
                            ushort_t* __restrict__ Wp, float* __restrict__ bias) {
    __shared__ float red[128];
    int o = blockIdx.x;
    int k = threadIdx.x;
    const float* abs_[3] = {ab1, ab2, ab3};
    float dot = 0.f;
    #pragma unroll
    for (int i = 0; i < 3; ++i) {
        float w = Wlin[o * 384 + i * 128 + k];
        Wp[o * 384 + i * 128 + k] = f2bf(w * abs_[i][k]);
        dot += w * abs_[i][128 + k];
    }
    red[k] = dot;
    __syncthreads();
    for (int s = 64; s > 0; s >>= 1) {
        if (k < s) red[k] += red[k + s];
        __syncthreads();
    }
    if (k == 0) bias[o] = blin[o] + red[0];
}

// ---------------- fused per-layer kernel: gather-mean + GEMM + BN stats -----
// out = relu([mean_nb(BN?(xin)) | xin] @ Wpack.T + bias), stats accumulated.
// 512 threads, node tile 128, out tile 128, K=256 fully LDS-resident.
// Gather: 4 threads/node, 32 ch each, fp32 acc -> bf16 swizzled A-tile.
// Waves: 2 node-strips(64) x 4 out-strips(32); acc 4x2 f32x4.

template<bool FOLD>
__global__ __launch_bounds__(512, 1) void k_fused(
    const ushort_t* __restrict__ xin,
    const int* __restrict__ row_ptr, const int* __restrict__ csr,
    const float* __restrict__ ab,
    const ushort_t* __restrict__ W, const float* __restrict__ bias,
    ushort_t* __restrict__ out, float* __restrict__ bn_sums)
{
    __shared__ __align__(16) ushort_t Abuf[2][128 * 128]; // [0]=aggr(k<128) [1]=x(k>=128)
    __shared__ __align__(16) ushort_t Wbuf[128 * 256];
    __shared__ float bns[128], bnq[128];

    const int tid = threadIdx.x;
    const int bn0 = blockIdx.x * 128;

    if (tid < 128) { bns[tid] = 0.f; bnq[tid] = 0.f; }

    // ---- stage W [128][256] and root-x tile [128][128] (pre-swizzled src) ----
    #pragma unroll
    for (int i = 0; i < 8; ++i) {
        int f = i * 512 + tid;            // 16B slot in Wbuf
        int row = f >> 5, sl = f & 31;
        int ssl = sl ^ (row & 7);
        __builtin_amdgcn_global_load_lds(
            (const __attribute__((address_space(1))) unsigned int*)(W + row * 256 + ssl * 8),
            (__attribute__((address_space(3))) unsigned int*)(&Wbuf[f * 8]), 16, 0, 0);
    }
    #pragma unroll
    for (int i = 0; i < 4; ++i) {
        int f = i * 512 + tid;            // 16B slot in Abuf[1]
        int row = f >> 4, sl = f & 15;
        int ssl = sl ^ (row & 7);
        int gr = bn0 + row; gr = gr < NN ? gr : NN - 1;
        __builtin_amdgcn_global_load_lds(
            (const __attribute__((address_space(1))) unsigned int*)(xin + (size_t)gr * CH + ssl * 8),
            (__attribute__((address_space(3))) unsigned int*)(&Abuf[1][f * 8]), 16, 0, 0);
    }

    // ---- gather-mean (overlaps the async staging above) ----
    {
        int node = bn0 + (tid >> 2);
        node = node < NN ? node : NN - 1;
        const int cb = (tid & 3) * 32;    // channel base for this thread
        const int r0 = row_ptr[node], r1 = row_ptr[node + 1];
        float ga[32];
        #pragma unroll
        for (int c = 0; c < 32; ++c) ga[c] = 0.f;
        int j = r0;
        for (; j + 1 < r1; j += 2) {
            int s0 = csr[j], s1 = csr[j + 1];
            const u16x8* p0 = (const u16x8*)(xin + (size_t)s0 * CH + cb);
            const u16x8* p1 = (const u16x8*)(xin + (size_t)s1 * CH + cb);
            u16x8 va[4], vb[4];
            #pragma unroll
            for (int u = 0; u < 4; ++u) { va[u] = p0[u]; vb[u] = p1[u]; }
            #pragma unroll
            for (int u = 0; u < 4; ++u)
                #pragma unroll
                for (int c = 0; c < 8; ++c)
                    ga[u * 8 + c] += bf2f(va[u][c]) + bf2f(vb[u][c]);
        }
        if (j < r1) {
            int s0 = csr[j];
            const u16x8* p0 = (const u16x8*)(xin + (size_t)s0 * CH + cb);
            u16x8 va[4];
            #pragma unroll
            for (int u = 0; u < 4; ++u) va[u] = p0[u];
            #pragma unroll
            for (int u = 0; u < 4; ++u)
                #pragma unroll
                for (int c = 0; c < 8; ++c)
                    ga[u * 8 + c] += bf2f(va[u][c]);
        }
        const int deg = r1 - r0;
        const float sc = deg > 0 ? 1.0f / (float)deg : 0.0f;
        const int row = tid >> 2;
        #pragma unroll
        for (int u = 0; u < 4; ++u) {
            u16x8 ov;
            #pragma unroll
            for (int c = 0; c < 8; ++c) {
                float v = ga[u * 8 + c] * sc;
                if (FOLD)
                    v = deg > 0 ? fmaf(v, ab[cb + u * 8 + c], ab[128 + cb + u * 8 + c]) : 0.f;
                ov[c] = f2bf(v);
            }
            int sl = (cb >> 3) + u;
            *(u16x8*)&Abuf[0][row * 128 + (sl ^ (row & 7)) * 8] = ov;
        }
    }

    asm volatile("s_waitcnt vmcnt(0)");
    __syncthreads();

    // ---- MFMA: 8 k-steps of 32 over the resident K=256 ----
    const int lane = tid & 63;
    const int wid  = tid >> 6;
    const int l15 = lane & 15, lg = lane >> 4;
    const int wn = (wid >> 2) * 64;       // node strip (2 x 64)
    const int wo = (wid & 3) * 32;        // out strip (4 x 32)

    f32x4 acc[4][2];
    #pragma unroll
    for (int i = 0; i < 4; ++i)
        #pragma unroll
        for (int j = 0; j < 2; ++j)
            acc[i][j] = (f32x4){0.f, 0.f, 0.f, 0.f};

    #pragma unroll
    for (int s = 0; s < 8; ++s) {
        const int half = s >> 2, sh = s & 3;
        short8_t af[4], wf[2];
        #pragma unroll
        for (int i = 0; i < 4; ++i) {
            int r = wn + i * 16 + l15;
            int sl = (sh * 4 + lg) ^ (r & 7);
            af[i] = *(const short8_t*)&Abuf[half][r * 128 + sl * 8];
        }
        #pragma unroll
        for (int j = 0; j < 2; ++j) {
            int r = wo + j * 16 + l15;
            int sl = (s * 4 + lg) ^ (r & 7);
            wf[j] = *(const short8_t*)&Wbuf[r * 256 + sl * 8];
        }
        #pragma unroll
        for (int i = 0; i < 4; ++i)
            #pragma unroll
            for (int j = 0; j < 2; ++j)
                acc[i][j] = __builtin_amdgcn_mfma_f32_16x16x32_bf16(
                    af[i], wf[j], acc[i][j], 0, 0, 0);
    }

    // ---- epilogue: bias + relu + store + BN partial sums ----
    float bv[2];
    #pragma unroll
    for (int j = 0; j < 2; ++j) bv[j] = bias[wo + j * 16 + l15];

    float sum[2] = {0.f, 0.f}, sq[2] = {0.f, 0.f};
    #pragma unroll
    for (int i = 0; i < 4; ++i) {
        #pragma unroll
        for (int r = 0; r < 4; ++r) {
            int gn = bn0 + wn + i * 16 + lg * 4 + r;
            bool ok = gn < NN;
            #pragma unroll
            for (int j = 0; j < 2; ++j) {
                float v = acc[i][j][r] + bv[j];
                v = fmaxf(v, 0.f);
                if (ok) {
                    out[(size_t)gn * CH + wo + j * 16 + l15] = f2bf(v);
                    sum[j] += v; sq[j] += v * v;
                }
            }
        }
    }

    #pragma unroll
    for (int j = 0; j < 2; ++j) {
        float ss = sum[j], qq = sq[j];
        ss += __shfl_xor(ss, 16); qq += __shfl_xor(qq, 16);
        ss += __shfl_xor(ss, 32); qq += __shfl_xor(qq, 32);
        if (lg == 0) {
            atomicAdd(&bns[wo + j * 16 + l15], ss);
            atomicAdd(&bnq[wo + j * 16 + l15], qq);
        }
    }
    __syncthreads();
    if (tid < 128) {
        atomicAdd(&bn_sums[tid], bns[tid]);
        atomicAdd(&bn_sums[128 + tid], bnq[tid]);
    }
}

// ---------------- final MFMA GEMM (unchanged, verified) ----------------

#define STAGE(buf, t) do {                                                           \
    const ushort_t* Ab_ = (((t) >> 1) == 0) ? A0 : ((((t) >> 1) == 1) ? A1 : A2);    \
    Ab_ += ((t) & 1) * 64;                                                           \
    const ushort_t* Wb_ = W + (t) * 64;                                              \
    _Pragma("unroll")                                                                \
    for (int i_ = 0; i_ < 4; ++i_) {                                                 \
        int f_ = i_ * 256 + tid;                                                     \
        int row_ = f_ >> 3;                                                          \
        int c_ = (f_ & 7) ^ (row_ & 7);                                              \
        int gr_ = bn0 + row_; gr_ = gr_ < NN ? gr_ : NN - 1;                         \
        __builtin_amdgcn_global_load_lds(                                            \
            (const __attribute__((address_space(1))) unsigned int*)(Ab_ + (size_t)gr_ * CH + c_ * 8), \
            (__attribute__((address_space(3))) unsigned int*)(&Abuf[buf][f_ * 8]),   \
            16, 0, 0);                                                               \
        __builtin_amdgcn_global_load_lds(                                            \
            (const __attribute__((address_space(1))) unsigned int*)(Wb_ + (size_t)row_ * (NT * 64) + c_ * 8), \
            (__attribute__((address_space(3))) unsigned int*)(&Wbuf[buf][f_ * 8]),   \
            16, 0, 0);                                                               \
    } } while (0)

template<int NT>
__global__ __launch_bounds__(256, 2) void k_mgemm(
    const ushort_t* __restrict__ A0, const ushort_t* __restrict__ A1,
    const ushort_t* __restrict__ A2,
    const ushort_t* __restrict__ W, const float* __restrict__ bias,
    float* __restrict__ outf)
{
    __shared__ __align__(16) ushort_t Abuf[2][128 * 64];
    __shared__ __align__(16) ushort_t Wbuf[2][128 * 64];

    const int tid  = threadIdx.x;
    const int lane = tid & 63;
    const int wid  = tid >> 6;
    const int l15  = lane & 15;
    const int lg   = lane >> 4;
    const int wn   = (wid >> 1) * 64;
    const int wo   = (wid & 1) * 64;
    const int bn0  = blockIdx.x * 128;

    f32x4 acc[4][4];
    #pragma unroll
    for (int i = 0; i < 4; ++i)
        #pragma unroll
        for (int j = 0; j < 4; ++j)
            acc[i][j] = (f32x4){0.f, 0.f, 0.f, 0.f};

    STAGE(0, 0);
    asm volatile("s_waitcnt vmcnt(0)");
    __syncthreads();

    #pragma unroll
    for (int t = 0; t < NT; ++t) {
        const int cur = t & 1;
        if (t + 1 < NT) STAGE(cur ^ 1, t + 1);
        #pragma unroll
        for (int s = 0; s < 2; ++s) {
            short8_t af[4], wf[4];
            #pragma unroll
            for (int b = 0; b < 4; ++b) {
                int ra = wn + b * 16 + l15;
                int ca = (s * 4 + lg) ^ (ra & 7);
                af[b] = *(const short8_t*)&Abuf[cur][ra * 64 + ca * 8];
                int rw = wo + b * 16 + l15;
                int cw = (s * 4 + lg) ^ (rw & 7);
                wf[b] = *(const short8_t*)&Wbuf[cur][rw * 64 + cw * 8];
            }
            #pragma unroll
            for (int i = 0; i < 4; ++i)
                #pragma unroll
                for (int j = 0; j < 4; ++j)
                    acc[i][j] = __builtin_amdgcn_mfma_f32_16x16x32_bf16(
                        af[i], wf[j], acc[i][j], 0, 0, 0);
        }
        asm volatile("s_waitcnt vmcnt(0)");
        __syncthreads();
    }

    float bv[4];
    #pragma unroll
    for (int j = 0; j < 4; ++j) bv[j] = bias[wo + j * 16 + l15];

    #pragma unroll
    for (int i = 0; i < 4; ++i) {
        #pragma unroll
        for (int r = 0; r < 4; ++r) {
            int gn = bn0 + wn + i * 16 + lg * 4 + r;
            if (gn < NN) {
                #pragma unroll
                for (int j = 0; j < 4; ++j) {
                    float v = acc[i][j][r] + bv[j];
                    outf[(size_t)gn * CH + wo + j * 16 + l15] = fmaxf(v, 0.f);
                }
            }
        }
    }
}

// ---------------- BN finalize: ab = {a = g*rstd, c = b - a*mu} --------------

__global__ void k_bnfin(const float* __restrict__ bn_sums, const float* __restrict__ g,
                        const float* __restrict__ b, float* __restrict__ ab) {
    int o = threadIdx.x;
    float mu = bn_sums[o] * (1.0f / NN);
    float var = bn_sums[128 + o] * (1.0f / NN) - mu * mu;
    var = var > 0.f ? var : 0.f;
    float rstd = rsqrtf(var + EPSV);
    float a = g[o] * rstd;
    ab[o] = a;
    ab[128 + o] = b[o] - a * mu;
}

// ---------------- driver ----------------

extern "C" void kernel_launch(void* const* d_in, const int* in_sizes, int n_in,
                              void* d_out, int out_size, void* d_ws, size_t ws_size,
                              hipStream_t stream) {
    const float* x  = (const float*)d_in[0];
    const int*   ei = (const int*)d_in[1];
    const int* esrc = ei;
    const int* edst = ei + NE;

    const float* Wl[3] = {(const float*)d_in[2],  (const float*)d_in[7],  (const float*)d_in[12]};
    const float* bl[3] = {(const float*)d_in[3],  (const float*)d_in[8],  (const float*)d_in[13]};
    const float* Wr[3] = {(const float*)d_in[4],  (const float*)d_in[9],  (const float*)d_in[14]};
    const float* gg[3] = {(const float*)d_in[5],  (const float*)d_in[10], (const float*)d_in[15]};
    const float* bb[3] = {(const float*)d_in[6],  (const float*)d_in[11], (const float*)d_in[16]};
    const float* Wlin  = (const float*)d_in[17];
    const float* blin  = (const float*)d_in[18];

    float* fo = (float*)d_out;

    const size_t NC = (size_t)NN * CH;
    ushort_t* xb   = (ushort_t*)d_ws;
    ushort_t* y1b  = xb + NC;
    ushort_t* y2b  = y1b + NC;
    ushort_t* y3b  = y2b + NC;
    ushort_t* Wp1  = y3b + NC;                 // [128][256]
    ushort_t* Wp2  = Wp1 + 128 * 256;
    ushort_t* Wp3  = Wp2 + 128 * 256;
    ushort_t* WpF  = Wp3 + 128 * 256;          // [128][384]
    float* bias2   = (float*)(WpF + 128 * 384);
    float* bias3   = bias2 + 128;
    float* biasF   = bias3 + 128;
    float* bn_sums = biasF + 128;              // 3 x 256
    float* ab      = bn_sums + 768;            // 3 x 256
    int* row_ptr   = (int*)(ab + 768);
    int* fillc     = row_ptr + NN + 1;
    int* csr       = fillc + NN;

    // ---- CSR build (bucketed passes for write locality) ----
    hipMemsetAsync(fillc, 0, NN * sizeof(int), stream);
    for (int p = 0; p < NPASS; ++p)
        k_histp<<<NE / 256, 256, 0, stream>>>(edst, fillc, p * PRANGE, (p + 1) * PRANGE);
    k_scan<<<1, 1024, 0, stream>>>(fillc, row_ptr);
    hipMemsetAsync(fillc, 0, NN * sizeof(int), stream);
    for (int p = 0; p < NPASS; ++p)
        k_fillp<<<NE / 256, 256, 0, stream>>>(esrc, edst, row_ptr, fillc, csr,
                                              p * PRANGE, (p + 1) * PRANGE);

    // ---- conversions / packs / stats zero ----
    k_cvtX<<<(NN * 32 + 255) / 256, 256, 0, stream>>>(x, xb);
    k_pack2<<<128, 256, 0, stream>>>(Wl[0], Wr[0], Wp1);
    hipMemsetAsync(bn_sums, 0, 768 * sizeof(float), stream);

    const int FUSE_GRID = (NN + 127) / 128;    // 391

    // ---- layer 1 ----
    k_fused<false><<<FUSE_GRID, 512, 0, stream>>>(
        xb, row_ptr, csr, nullptr, Wp1, bl[0], y1b, bn_sums);
    k_bnfin<<<1, 128, 0, stream>>>(bn_sums, gg[0], bb[0], ab);
    k_packfold<<<128, 128, 0, stream>>>(Wl[1], Wr[1], ab, bl[1], Wp2, bias2);

    // ---- layer 2 ----
    k_fused<true><<<FUSE_GRID, 512, 0, stream>>>(
        y1b, row_ptr, csr, ab, Wp2, bias2, y2b, bn_sums + 256);
    k_bnfin<<<1, 128, 0, stream>>>(bn_sums + 256, gg[1], bb[1], ab + 256);
    k_packfold<<<128, 128, 0, stream>>>(Wl[2], Wr[2], ab + 256, bl[2], Wp3, bias3);

    // ---- layer 3 ----
    k_fused<true><<<FUSE_GRID, 512, 0, stream>>>(
        y2b, row_ptr, csr, ab + 256, Wp3, bias3, y3b, bn_sums + 512);
    k_bnfin<<<1, 128, 0, stream>>>(bn_sums + 512, gg[2], bb[2], ab + 512);
    k_packfoldF<<<128, 128, 0, stream>>>(Wlin, ab, ab + 256, ab + 512, blin, WpF, biasF);

    // ---- final: relu([y1|y2|y3] @ WpF.T + biasF) -> fp32 d_out ----
    k_mgemm<6><<<FUSE_GRID, 256, 0, stream>>>(y1b, y2b, y3b, WpF, biasF, fo);
}

// Round 5
// 362.676 us; speedup vs baseline: 1.8564x; 1.0143x over previous
//
#include <hip/hip_runtime.h>

#define NN 50000
#define NE 800000
#define CH 128
#define EPSV 1e-5f
#define NPASS 2
#define PRANGE 25000

typedef unsigned short ushort_t;
typedef __attribute__((ext_vector_type(8))) short short8_t;
typedef __attribute__((ext_vector_type(8))) unsigned short u16x8;
typedef __attribute__((ext_vector_type(4))) float f32x4;

__device__ inline float bf2f(ushort_t u) {
    union { unsigned int i; float f; } t; t.i = ((unsigned int)u) << 16; return t.f;
}
__device__ inline ushort_t f2bf(float f) {
    union { float f; unsigned int i; } t; t.f = f;
    unsigned int r = t.i + 0x7fff + ((t.i >> 16) & 1);   // round-to-nearest-even
    return (ushort_t)(r >> 16);
}

// ---------------- CSR build ----------------

__global__ void k_hist(const int* __restrict__ dst, int* __restrict__ deg) {
    int e = blockIdx.x * 256 + threadIdx.x;
    if (e < NE) atomicAdd(&deg[dst[e]], 1);
}

// exclusive scan over deg -> row_ptr; also zeroes deg (it is fillc) in-flight
__global__ void k_scan(int* __restrict__ deg, int* __restrict__ row_ptr) {
    __shared__ int wsum[16];
    const int t = threadIdx.x;
    const int lane = t & 63;
    const int wid = t >> 6;
    int carry = 0;
    for (int base = 0; base < NN; base += 1024) {
        int i = base + t;
        int v = (i < NN) ? deg[i] : 0;
        if (i < NN) deg[i] = 0;
        int x = v;
        #pragma unroll
        for (int off = 1; off < 64; off <<= 1) {
            int y = __shfl_up(x, off, 64);
            if (lane >= off) x += y;
        }
        if (lane == 63) wsum[wid] = x;
        __syncthreads();
        if (wid == 0 && lane < 16) {
            int s = wsum[lane];
            #pragma unroll
            for (int off = 1; off < 16; off <<= 1) {
                int y = __shfl_up(s, off, 16);
                if (lane >= off) s += y;
            }
            wsum[lane] = s;
        }
        __syncthreads();
        int wbase = (wid > 0) ? wsum[wid - 1] : 0;
        if (i < NN) row_ptr[i] = carry + wbase + x - v;
        carry += wsum[15];
        __syncthreads();
    }
    if (t == 0) row_ptr[NN] = carry;
}

__global__ void k_fillp(const int* __restrict__ src, const int* __restrict__ dst,
                        const int* __restrict__ row_ptr, int* __restrict__ fillc,
                        int* __restrict__ csr, int lo, int hi) {
    int e = blockIdx.x * 256 + threadIdx.x;
    if (e < NE) {
        int d = dst[e];
        int s = src[e];
        if (d >= lo && d < hi) {
            int pos = row_ptr[d] + atomicAdd(&fillc[d], 1);
            csr[pos] = s;
        }
    }
}

// ---------------- conversions / weight packing ----------------

// also zeroes bn_sums (block 0) so no separate memset dispatch is needed
__global__ __launch_bounds__(256) void k_cvtX(const float* __restrict__ x,
                                              ushort_t* __restrict__ xb,
                                              float* __restrict__ bn_sums) {
    int i = blockIdx.x * 256 + threadIdx.x;      // float4 index
    if (blockIdx.x == 0) {
        bn_sums[threadIdx.x] = 0.f;
        bn_sums[256 + threadIdx.x] = 0.f;
        bn_sums[512 + threadIdx.x] = 0.f;
    }
    if (i >= NN * 32) return;
    float4 v = ((const float4*)x)[i];
    ushort4 o;
    o.x = f2bf(v.x); o.y = f2bf(v.y); o.z = f2bf(v.z); o.w = f2bf(v.w);
    ((ushort4*)xb)[i] = o;
}

// plain pack [Wl | Wr] -> dst[o][256] bf16 (layer 1, no BN fold)
__global__ __launch_bounds__(256) void k_pack2(const float* __restrict__ s0,
                                               const float* __restrict__ s1,
                                               ushort_t* __restrict__ dst) {
    int t = blockIdx.x * 256 + threadIdx.x;      // 128*256
    if (t >= 128 * 256) return;
    int o = t >> 8, k = t & 255;
    float v = (k < 128) ? s0[o * 128 + k] : s1[o * 128 + k - 128];
    dst[t] = f2bf(v);
}

// fused BN-finalize + next-layer fold:
//   a = g*rsqrt(var+eps), c = b - a*mu  (from bn_sums of layer l)
//   Wp_{l+1} = [Wl | Wr*a], bias_{l+1} = bl + Wr@c; block 0 stores {a,c} -> abg
__global__ void k_foldnext(const float* __restrict__ bn_sums,
                           const float* __restrict__ g, const float* __restrict__ b,
                           const float* __restrict__ Wl, const float* __restrict__ Wr,
                           const float* __restrict__ bl,
                           ushort_t* __restrict__ Wp, float* __restrict__ bias,
                           float* __restrict__ abg) {
    __shared__ float red[128];
    int o = blockIdx.x;
    int k = threadIdx.x;
    float mu = bn_sums[k] * (1.0f / NN);
    float var = bn_sums[128 + k] * (1.0f / NN) - mu * mu;
    var = var > 0.f ? var : 0.f;
    float a = g[k] * rsqrtf(var + EPSV);
    float c = b[k] - a * mu;
    if (o == 0) { abg[k] = a; abg[128 + k] = c; }
    float wr = Wr[o * 128 + k];
    Wp[o * 256 + k]       = f2bf(Wl[o * 128 + k]);
    Wp[o * 256 + 128 + k] = f2bf(wr * a);
    red[k] = wr * c;
    __syncthreads();
    for (int s = 64; s > 0; s >>= 1) {
        if (k < s) red[k] += red[k + s];
        __syncthreads();
    }
    if (k == 0) bias[o] = bl[o] + red[0];
}

// final fold: layer-3 BN finalize + Wlin fold (uses stored ab1, ab2)
__global__ void k_foldF(const float* __restrict__ bn3,
                        const float* __restrict__ g3, const float* __restrict__ b3,
                        const float* __restrict__ ab1, const float* __restrict__ ab2,
                        const float* __restrict__ Wlin, const float* __restrict__ blin,
                        ushort_t* __restrict__ Wp, float* __restrict__ bias) {
    __shared__ float red[128];
    int o = blockIdx.x;
    int k = threadIdx.x;
    float mu = bn3[k] * (1.0f / NN);
    float var = bn3[128 + k] * (1.0f / NN) - mu * mu;
    var = var > 0.f ? var : 0.f;
    float a3 = g3[k] * rsqrtf(var + EPSV);
    float c3 = b3[k] - a3 * mu;
    float w1 = Wlin[o * 384 + k];
    float w2 = Wlin[o * 384 + 128 + k];
    float w3 = Wlin[o * 384 + 256 + k];
    Wp[o * 384 + k]       = f2bf(w1 * ab1[k]);
    Wp[o * 384 + 128 + k] = f2bf(w2 * ab2[k]);
    Wp[o * 384 + 256 + k] = f2bf(w3 * a3);
    red[k] = w1 * ab1[128 + k] + w2 * ab2[128 + k] + w3 * c3;
    __syncthreads();
    for (int s = 64; s > 0; s >>= 1) {
        if (k < s) red[k] += red[k + s];
        __syncthreads();
    }
    if (k == 0) bias[o] = blin[o] + red[0];
}

// ---------------- mean aggregation: one wave per node, 16B/lane gather ------
// 16 lanes cover one 256B row; 4 quarters x 4 streams = 16 edges per wave-iter
// (4 independent row-loads in flight per lane). FOLD: BN affine folded in.

template<bool FOLD>
__global__ __launch_bounds__(256) void k_aggr(const ushort_t* __restrict__ x,
        const int* __restrict__ row_ptr, const int* __restrict__ csr,
        const float* __restrict__ ab, ushort_t* __restrict__ aggr) {
    const int node = blockIdx.x * 4 + (threadIdx.x >> 6);   // grid = NN/4 exact
    const int lane = threadIdx.x & 63;
    const int l4 = lane & 15;        // channel group: ch l4*8 .. l4*8+7
    const int q  = lane >> 4;        // edge phase 0..3
    const int r0 = row_ptr[node], r1 = row_ptr[node + 1];
    const int d = r1 - r0;
    const ushort_t* xrow = x + l4 * 8;

    float accA[8] = {0, 0, 0, 0, 0, 0, 0, 0};
    float accB[8] = {0, 0, 0, 0, 0, 0, 0, 0};

    int j = r0 + q;
    for (; j + 12 < r1; j += 16) {   // 16 edges per wave-iter (4 per quarter)
        int s0 = csr[j], s1 = csr[j + 4], s2 = csr[j + 8], s3 = csr[j + 12];
        u16x8 v0 = *(const u16x8*)(xrow + (size_t)s0 * CH);
        u16x8 v1 = *(const u16x8*)(xrow + (size_t)s1 * CH);
        u16x8 v2 = *(const u16x8*)(xrow + (size_t)s2 * CH);
        u16x8 v3 = *(const u16x8*)(xrow + (size_t)s3 * CH);
        #pragma unroll
        for (int i = 0; i < 8; ++i) {
            accA[i] += bf2f(v0[i]) + bf2f(v1[i]);
            accB[i] += bf2f(v2[i]) + bf2f(v3[i]);
        }
    }
    for (; j < r1; j += 4) {
        int s0 = csr[j];
        u16x8 v0 = *(const u16x8*)(xrow + (size_t)s0 * CH);
        #pragma unroll
        for (int i = 0; i < 8; ++i) accA[i] += bf2f(v0[i]);
    }

    const float sc = d > 0 ? 1.0f / (float)d : 0.0f;
    #pragma unroll
    for (int i = 0; i < 8; ++i) {
        float s = accA[i] + accB[i];
        s += __shfl_xor(s, 16);
        s += __shfl_xor(s, 32);
        accA[i] = s * sc;
    }

    if (q == 0) {
        u16x8 ov;
        #pragma unroll
        for (int i = 0; i < 8; ++i) {
            float v = accA[i];
            if (FOLD) v = d > 0 ? fmaf(v, ab[l4 * 8 + i], ab[128 + l4 * 8 + i]) : 0.f;
            ov[i] = f2bf(v);
        }
        *(u16x8*)&aggr[(size_t)node * CH + l4 * 8] = ov;
    }
}

// ---------------- MFMA GEMM: out = relu([A0|A1|A2] @ Wpack.T + bias) --------
// A logically concatenated along K (NT tiles of 64). Wpack: [128][NT*64] bf16.
// Block: 128 nodes x 128 outs, 4 waves at 64x64. LDS XOR-swizzled (T2) via
// pre-swizzled global source (rule 21): linear dest + c^(row&7) src + swz read.

#define STAGE(buf, t) do {                                                           \
    const ushort_t* Ab_ = (((t) >> 1) == 0) ? A0 : ((((t) >> 1) == 1) ? A1 : A2);    \
    Ab_ += ((t) & 1) * 64;                                                           \
    const ushort_t* Wb_ = W + (t) * 64;                                              \
    _Pragma("unroll")                                                                \
    for (int i_ = 0; i_ < 4; ++i_) {                                                 \
        int f_ = i_ * 256 + tid;                                                     \
        int row_ = f_ >> 3;                                                          \
        int c_ = (f_ & 7) ^ (row_ & 7);                                              \
        int gr_ = bn0 + row_; gr_ = gr_ < NN ? gr_ : NN - 1;                         \
        __builtin_amdgcn_global_load_lds(                                            \
            (const __attribute__((address_space(1))) unsigned int*)(Ab_ + (size_t)gr_ * CH + c_ * 8), \
            (__attribute__((address_space(3))) unsigned int*)(&Abuf[buf][f_ * 8]),   \
            16, 0, 0);                                                               \
        __builtin_amdgcn_global_load_lds(                                            \
            (const __attribute__((address_space(1))) unsigned int*)(Wb_ + (size_t)row_ * (NT * 64) + c_ * 8), \
            (__attribute__((address_space(3))) unsigned int*)(&Wbuf[buf][f_ * 8]),   \
            16, 0, 0);                                                               \
    } } while (0)

template<int NT, bool STATS, bool F32OUT>
__global__ __launch_bounds__(256, 2) void k_mgemm(
    const ushort_t* __restrict__ A0, const ushort_t* __restrict__ A1,
    const ushort_t* __restrict__ A2,
    const ushort_t* __restrict__ W, const float* __restrict__ bias,
    ushort_t* __restrict__ outb, float* __restrict__ outf,
    float* __restrict__ bn_sums)
{
    __shared__ __align__(16) ushort_t Abuf[2][128 * 64];
    __shared__ __align__(16) ushort_t Wbuf[2][128 * 64];
    __shared__ float bns[128], bnq[128];

    const int tid  = threadIdx.x;
    const int lane = tid & 63;
    const int wid  = tid >> 6;
    const int l15  = lane & 15;
    const int lg   = lane >> 4;
    const int wn   = (wid >> 1) * 64;   // wave node-origin within tile
    const int wo   = (wid & 1) * 64;    // wave out-origin within tile
    const int bn0  = blockIdx.x * 128;

    if (STATS && tid < 128) { bns[tid] = 0.f; bnq[tid] = 0.f; }

    f32x4 acc[4][4];
    #pragma unroll
    for (int i = 0; i < 4; ++i)
        #pragma unroll
        for (int j = 0; j < 4; ++j)
            acc[i][j] = (f32x4){0.f, 0.f, 0.f, 0.f};

    STAGE(0, 0);
    asm volatile("s_waitcnt vmcnt(0)");
    __syncthreads();

    #pragma unroll
    for (int t = 0; t < NT; ++t) {
        const int cur = t & 1;
        if (t + 1 < NT) STAGE(cur ^ 1, t + 1);
        #pragma unroll
        for (int s = 0; s < 2; ++s) {
            short8_t af[4], wf[4];
            #pragma unroll
            for (int b = 0; b < 4; ++b) {
                int ra = wn + b * 16 + l15;
                int ca = (s * 4 + lg) ^ (ra & 7);
                af[b] = *(const short8_t*)&Abuf[cur][ra * 64 + ca * 8];
                int rw = wo + b * 16 + l15;
                int cw = (s * 4 + lg) ^ (rw & 7);
                wf[b] = *(const short8_t*)&Wbuf[cur][rw * 64 + cw * 8];
            }
            #pragma unroll
            for (int i = 0; i < 4; ++i)
                #pragma unroll
                for (int j = 0; j < 4; ++j)
                    acc[i][j] = __builtin_amdgcn_mfma_f32_16x16x32_bf16(
                        af[i], wf[j], acc[i][j], 0, 0, 0);
        }
        asm volatile("s_waitcnt vmcnt(0)");
        __syncthreads();
    }

    // epilogue: bias + relu + store (+ BN stats from fp32 acc)
    float bv[4];
    #pragma unroll
    for (int j = 0; j < 4; ++j) bv[j] = bias[wo + j * 16 + l15];

    float sum[4] = {0.f, 0.f, 0.f, 0.f}, sq[4] = {0.f, 0.f, 0.f, 0.f};

    #pragma unroll
    for (int i = 0; i < 4; ++i) {
        #pragma unroll
        for (int r = 0; r < 4; ++r) {
            int gn = bn0 + wn + i * 16 + lg * 4 + r;
            bool ok = gn < NN;
            #pragma unroll
            for (int j = 0; j < 4; ++j) {
                int o = wo + j * 16 + l15;
                float v = acc[i][j][r] + bv[j];
                v = fmaxf(v, 0.f);
                if (ok) {
                    if (F32OUT) outf[(size_t)gn * CH + o] = v;
                    else        outb[(size_t)gn * CH + o] = f2bf(v);
                    if (STATS) { sum[j] += v; sq[j] += v * v; }
                }
            }
        }
    }

    if (STATS) {
        #pragma unroll
        for (int j = 0; j < 4; ++j) {
            float ss = sum[j], qq = sq[j];
            ss += __shfl_xor(ss, 16); qq += __shfl_xor(qq, 16);
            ss += __shfl_xor(ss, 32); qq += __shfl_xor(qq, 32);
            if (lg == 0) {
                atomicAdd(&bns[wo + j * 16 + l15], ss);
                atomicAdd(&bnq[wo + j * 16 + l15], qq);
            }
        }
        __syncthreads();
        if (tid < 128) {
            atomicAdd(&bn_sums[tid], bns[tid]);
            atomicAdd(&bn_sums[128 + tid], bnq[tid]);
        }
    }
}

// ---------------- driver ----------------

extern "C" void kernel_launch(void* const* d_in, const int* in_sizes, int n_in,
                              void* d_out, int out_size, void* d_ws, size_t ws_size,
                              hipStream_t stream) {
    const float* x  = (const float*)d_in[0];
    const int*   ei = (const int*)d_in[1];
    const int* esrc = ei;
    const int* edst = ei + NE;

    const float* Wl[3] = {(const float*)d_in[2],  (const float*)d_in[7],  (const float*)d_in[12]};
    const float* bl[3] = {(const float*)d_in[3],  (const float*)d_in[8],  (const float*)d_in[13]};
    const float* Wr[3] = {(const float*)d_in[4],  (const float*)d_in[9],  (const float*)d_in[14]};
    const float* gg[3] = {(const float*)d_in[5],  (const float*)d_in[10], (const float*)d_in[15]};
    const float* bb[3] = {(const float*)d_in[6],  (const float*)d_in[11], (const float*)d_in[16]};
    const float* Wlin  = (const float*)d_in[17];
    const float* blin  = (const float*)d_in[18];

    float* fo = (float*)d_out;

    const size_t NC = (size_t)NN * CH;
    ushort_t* xb     = (ushort_t*)d_ws;
    ushort_t* y1b    = xb + NC;
    ushort_t* y2b    = y1b + NC;
    ushort_t* y3b    = y2b + NC;
    ushort_t* aggr_b = y3b + NC;
    ushort_t* Wp1    = aggr_b + NC;            // [128][256]
    ushort_t* Wp2    = Wp1 + 128 * 256;
    ushort_t* Wp3    = Wp2 + 128 * 256;
    ushort_t* WpF    = Wp3 + 128 * 256;        // [128][384]
    float* bias2     = (float*)(WpF + 128 * 384);
    float* bias3     = bias2 + 128;
    float* biasF     = bias3 + 128;
    float* bn_sums   = biasF + 128;            // 3 x 256
    float* ab        = bn_sums + 768;          // 2 x 256 (layer-1, layer-2 {a,c})
    int* row_ptr     = (int*)(ab + 512);
    int* fillc       = row_ptr + NN + 1;
    int* csr         = fillc + NN;

    // ---- CSR build ----
    hipMemsetAsync(fillc, 0, NN * sizeof(int), stream);
    k_hist<<<(NE + 255) / 256, 256, 0, stream>>>(edst, fillc);
    k_scan<<<1, 1024, 0, stream>>>(fillc, row_ptr);        // also zeroes fillc
    for (int p = 0; p < NPASS; ++p)
        k_fillp<<<NE / 256, 256, 0, stream>>>(esrc, edst, row_ptr, fillc, csr,
                                              p * PRANGE, (p + 1) * PRANGE);

    // ---- conversions / packs (cvtX also zeroes bn_sums) ----
    k_cvtX<<<(NN * 32 + 255) / 256, 256, 0, stream>>>(x, xb, bn_sums);
    k_pack2<<<128, 256, 0, stream>>>(Wl[0], Wr[0], Wp1);

    const int GEMM_GRID = (NN + 127) / 128;    // 391

    // ---- layer 1 ----
    k_aggr<false><<<NN / 4, 256, 0, stream>>>(xb, row_ptr, csr, nullptr, aggr_b);
    k_mgemm<4, true, false><<<GEMM_GRID, 256, 0, stream>>>(
        aggr_b, xb, nullptr, Wp1, bl[0], y1b, nullptr, bn_sums);
    k_foldnext<<<128, 128, 0, stream>>>(bn_sums, gg[0], bb[0],
                                        Wl[1], Wr[1], bl[1], Wp2, bias2, ab);

    // ---- layer 2 ----
    k_aggr<true><<<NN / 4, 256, 0, stream>>>(y1b, row_ptr, csr, ab, aggr_b);
    k_mgemm<4, true, false><<<GEMM_GRID, 256, 0, stream>>>(
        aggr_b, y1b, nullptr, Wp2, bias2, y2b, nullptr, bn_sums + 256);
    k_foldnext<<<128, 128, 0, stream>>>(bn_sums + 256, gg[1], bb[1],
                                        Wl[2], Wr[2], bl[2], Wp3, bias3, ab + 256);

    // ---- layer 3 ----
    k_aggr<true><<<NN / 4, 256, 0, stream>>>(y2b, row_ptr, csr, ab + 256, aggr_b);
    k_mgemm<4, true, false><<<GEMM_GRID, 256, 0, stream>>>(
        aggr_b, y2b, nullptr, Wp3, bias3, y3b, nullptr, bn_sums + 512);
    k_foldF<<<128, 128, 0, stream>>>(bn_sums + 512, gg[2], bb[2], ab, ab + 256,
                                     Wlin, blin, WpF, biasF);

    // ---- final: relu([y1|y2|y3] @ WpF.T + biasF) -> fp32 d_out ----
    k_mgemm<6, false, true><<<GEMM_GRID, 256, 0, stream>>>(
        y1b, y2b, y3b, WpF, biasF, nullptr, fo, nullptr);
}